// Round 15
// baseline (76.758 us; speedup 1.0000x reference)
//
#include <hip/hip_runtime.h>
#include <math.h>

#define HH 100
#define HP 112
#define KP 136
#define BB 64
#define SS 384
#define EPSF 1e-6f
#define NCH 24                  // 16-j chunks; pass2 per pair (K=32)
#define QT16 4352               // ush per 16-j qT chunk (hi 16*KP | lo 16*KP) = 544 slots
#define QT_PITCH_B 9216         // qT buffer pitch (576 slots)
#define QHJ_OFF_B 18432         // qhj region offset (after 2 qT buffers)
#define QHJ_ROWP 40             // ush per qhj row (32 hi + 8 dup) = 5 slots
#define BNC_OFF_B 27392         // bounce offset
#define BNCP 36                 // bounce pitch (floats)
#define STATB_OFF_B 29696       // statb alias after loop
#define SMEM_B 36608

typedef __attribute__((ext_vector_type(8))) short bf16x8;
typedef __attribute__((ext_vector_type(4))) float f32x4;
typedef unsigned short ushort_t;

__device__ __forceinline__ ushort_t f2bf(float x) {
  unsigned u = __float_as_uint(x);
  unsigned r = (u + 0x7FFFu + ((u >> 16) & 1u)) >> 16;
  return (ushort_t)r;
}
__device__ __forceinline__ float bf2f(ushort_t h) {
  return __uint_as_float(((unsigned)h) << 16);
}
__device__ __forceinline__ void ld_g2l16(void* lds, const void* g) {
  __builtin_amdgcn_global_load_lds(
      (const __attribute__((address_space(1))) unsigned*)g,
      (__attribute__((address_space(3))) unsigned*)lds, 16, 0, 0);
}

// ---------------- Prep kernel: norms + qhj hi + 16j qT chunks ----------------
__global__ __launch_bounds__(256) void qprep_kernel(
    const float* __restrict__ qf, const float* __restrict__ qb,
    const float* __restrict__ w2f, const float* __restrict__ w2b,
    float* __restrict__ nq2, ushort_t* __restrict__ qhj_hi,
    ushort_t* __restrict__ qTil)
{
  __shared__ __align__(16) float tile[HH * 68];
  __shared__ float w2sq_s[HH][2];
  const int blk = blockIdx.x;
  const int dir = blk / (BB * 6);
  const int rem = blk % (BB * 6);
  const int b   = rem / 6;
  const int jt  = rem % 6;
  const int j0  = jt * 64;
  const float* q  = dir ? qb : qf;
  const float* w2 = dir ? w2b : w2f;
  const int t = threadIdx.x;
  if (t < HH) {
    float a = w2[t], c = w2[HH + t];
    w2sq_s[t][0] = a * a; w2sq_s[t][1] = c * c;
  }
  for (int e = t; e < HH * 16; e += 256) {
    int h = e >> 4, j4 = e & 15;
    float4 v = *(const float4*)&q[((size_t)h * BB + b) * SS + j0 + j4 * 4];
    *(float4*)&tile[h * 68 + j4 * 4] = v;
  }
  __syncthreads();
  // qT 16j-chunk-interleaved: [dir][b][chunk16][hi 16xKP | lo 16xKP]
  for (int e = t; e < 64 * KP; e += 256) {
    int jj = e / KP, kp = e % KP;
    float x = (kp < HH) ? tile[kp * 68 + jj] : 0.f;
    ushort_t hi = f2bf(x);
    int cg = jt * 4 + (jj >> 4);
    size_t base = ((size_t)(dir * BB + b) * NCH + cg) * QT16
                + (size_t)(jj & 15) * KP + kp;
    qTil[base] = hi;
    qTil[base + 16 * KP] = f2bf(x - bf2f(hi));
  }
  // qhj hi only (RNE), zero-padded h in [100,112)
  for (int e = t; e < HP * 64; e += 256) {
    int hp = e >> 6, jj = e & 63;
    float x = (hp < HH) ? tile[hp * 68 + jj] : 0.f;
    size_t o = ((size_t)(dir * HP + hp) * BB + b) * SS + j0 + jj;
    qhj_hi[o] = f2bf(x);
  }
  // reciprocal norms
  if (t < 64) {
    float s0 = 0.f, s1 = 0.f, sp = 0.f;
    for (int h = 0; h < HH; ++h) {
      float v = tile[h * 68 + t];
      float v2 = v * v;
      s0 = fmaf(w2sq_s[h][0], v2, s0);
      s1 = fmaf(w2sq_s[h][1], v2, s1);
      sp += v2;
    }
    int j = j0 + t;
    nq2[((size_t)(dir * 2 + 0) * BB + b) * SS + j] = 1.0f / fmaxf(sqrtf(s0), EPSF);
    nq2[((size_t)(dir * 2 + 1) * BB + b) * SS + j] = 1.0f / fmaxf(sqrtf(s1), EPSF);
    nq2[((size_t)(4 + dir) * BB + b) * SS + j]     = 1.0f / fmaxf(sqrtf(sp), EPSF);
  }
}

// ---------------- Main fused kernel: paired 16-j chunks ----------------
// __launch_bounds__(256, 3): (256,4) spilled hmD to scratch in R11 (2.2x
// slower). (256,3) compiles spill-free at 84-88 VGPR.
__global__ __launch_bounds__(256, 3) void bimpm_fused(
    const float* __restrict__ pf, const float* __restrict__ pb,
    const float* __restrict__ qf, const float* __restrict__ qb,
    const float* __restrict__ w1f, const float* __restrict__ w1b,
    const float* __restrict__ w2f, const float* __restrict__ w2b,
    const float* __restrict__ w3f_, const float* __restrict__ w4f_,
    const float* __restrict__ nq2ws,
    const ushort_t* __restrict__ qhj_hi, const ushort_t* __restrict__ qTil,
    float* __restrict__ out)
{
  __shared__ __align__(16) char smemc[SMEM_B];   // qT dbuf | qhj | bounce
  __shared__ __align__(16) float wsq[HH][8];     // 3200 B
  __shared__ __align__(16) float nqs[3 * SS];    // 4608 B (ra | rb | rp)
  __shared__ float qlast_s[HH];                  // 400 B

  float* hmbuf = (float*)smemc;                  // [64][116] after loop
  float* statb = (float*)(smemc + STATB_OFF_B);  // [4][16][4] after loop
  float* bounce = (float*)(smemc + BNC_OFF_B);

  // XCD-aware work swizzle: 768 = 8 * 96, bijective
  const int bid  = blockIdx.x;
  const int work = (bid & 7) * 96 + (bid >> 3);
  const int dir = work / (BB * 6);
  const int rem = work % (BB * 6);
  const int b   = rem / 6;
  const int i0  = (rem % 6) * 64;

  const float* __restrict__ p  = dir ? pb : pf;
  const float* __restrict__ q  = dir ? qb : qf;
  const float* __restrict__ w1 = dir ? w1b : w1f;
  const float* __restrict__ w2 = dir ? w2b : w2f;
  const int t = threadIdx.x;
  const int w = t >> 6, lane = t & 63, li = lane & 15, lg = lane >> 4;
  const int rowbase = i0 + w * 16;
  const size_t AS = (size_t)SS * BB * 2;
  const size_t qt_base = (size_t)(dir * BB + b) * NCH * QT16;
  const ushort_t* __restrict__ qhjH0 = qhj_hi + ((size_t)dir * HP * BB + b) * SS;

  if (t < HH) {
    float a, c;
    a = w1[t];   c = w1[HH + t];   wsq[t][0] = a*a; wsq[t][1] = c*c;
    a = w2[t];   c = w2[HH + t];   wsq[t][2] = a*a; wsq[t][3] = c*c;
    a = w3f_[t]; c = w3f_[HH + t]; wsq[t][4] = a*a; wsq[t][5] = c*c;
    a = w4f_[t]; c = w4f_[HH + t]; wsq[t][6] = a*a; wsq[t][7] = c*c;
    qlast_s[t] = q[(size_t)t * BB * SS + (size_t)b * SS + (SS - 1)];
  }
  // stage nq2 reciprocals into LDS (removes 3 L2 loads per chunk from stats chain)
  for (int e = t; e < SS; e += 256) {
    nqs[e]          = nq2ws[((size_t)(dir * 2 + 0) * BB + b) * SS + e];
    nqs[SS + e]     = nq2ws[((size_t)(dir * 2 + 1) * BB + b) * SS + e];
    nqs[2 * SS + e] = nq2ws[((size_t)(4 + dir) * BB + b) * SS + e];
  }

  // ---- async qT chunk stage: 544 slots, wave-balanced (136 per wave) ----
  auto stage_qt = [&](int cc, int bi) {
    char* dst = smemc + bi * QT_PITCH_B;
    const char* gsrc = (const char*)(qTil + qt_base + (size_t)cc * QT16);
#pragma unroll
    for (int k = 0; k < 2; ++k) {
      const int sb = k * 256 + w * 64;
      ld_g2l16(dst + (size_t)sb * 16, gsrc + (size_t)(sb + lane) * 16);
    }
    {
      const int sb = 512 + w * 8;        // tail 32 slots: 8 per wave
      if (lane < 8)
        ld_g2l16(dst + (size_t)sb * 16, gsrc + (size_t)(sb + lane) * 16);
    }
  };
  // ---- async qhj stage for pair P: 560 slots, wave-balanced ----
  // SCHEDULE: issued ONLY at the top of even chunk 2P (P=0 in prologue).
  // Pass-2 of pair P-1 finished before the barrier ending chunk 2P-1, so no
  // overwrite; the barrier ending chunk 2P drains vmcnt before pair P's reads
  // at the end of chunk 2P+1.
  auto stage_qhj = [&](int P) {
    char* dst = smemc + QHJ_OFF_B;
#pragma unroll
    for (int k = 0; k < 2; ++k) {
      const int sb = k * 256 + w * 64;
      int v = sb + lane;
      int hp = v / 5;
      int s = v - hp * 5;
      if (s == 4) s = 0;   // dup pad slot
      const ushort_t* src = qhjH0 + (size_t)hp * (BB * SS) + P * 32 + s * 8;
      ld_g2l16(dst + (size_t)sb * 16, src);
    }
    {
      const int sb = 512 + w * 12;       // tail 48 slots: 12 per wave
      if (lane < 12) {
        int v = sb + lane;
        int hp = v / 5;
        int s = v - hp * 5;
        if (s == 4) s = 0;
        const ushort_t* src = qhjH0 + (size_t)hp * (BB * SS) + P * 32 + s * 8;
        ld_g2l16(dst + (size_t)sb * 16, src);
      }
    }
  };

  stage_qt(0, 0);
  stage_qhj(0);

  // ---- p fragments in registers ----
  bf16x8 pHi[4], pLo[4], pGa[4], pGb[4];
#pragma unroll
  for (int kt = 0; kt < 4; ++kt) {
#pragma unroll
    for (int s = 0; s < 8; ++s) {
      int h = kt * 32 + 8 * lg + s;
      float pv = 0.f, ga = 0.f, gb = 0.f;
      if (h < HH) {
        pv = p[(size_t)h * BB * SS + (size_t)b * SS + rowbase + li];
        float wa = w2[h], wb = w2[HH + h];
        ga = pv * wa * wa;
        gb = pv * wb * wb;
      }
      ushort_t hi = f2bf(pv);
      pHi[kt][s] = (short)hi;
      pLo[kt][s] = (short)f2bf(pv - bf2f(hi));
      pGa[kt][s] = (short)f2bf(ga);
      pGb[kt][s] = (short)f2bf(gb);
    }
  }
  __syncthreads();   // buf0 + qhj(0) + nqs staged (barrier drains vmcnt)

  f32x4 hmD[7];
#pragma unroll
  for (int nt = 0; nt < 7; ++nt) hmD[nt] = (f32x4){0.f, 0.f, 0.f, 0.f};
  float rowsum[4] = {0, 0, 0, 0};
  float amax[4] = {-INFINITY, -INFINITY, -INFINITY, -INFINITY};
  float m2a[4] = {-INFINITY, -INFINITY, -INFINITY, -INFINITY};
  float m2b[4] = {-INFINITY, -INFINITY, -INFINITY, -INFINITY};
  int aidx[4] = {0, 0, 0, 0};
  float* bw = bounce + w * (16 * BNCP);
  const ushort_t* qjR = (const ushort_t*)(smemc + QHJ_OFF_B);

  for (int c = 0; c < NCH; ++c) {
    const bool evenc = (c & 1) == 0;
    if (c + 1 < NCH) stage_qt(c + 1, (c + 1) & 1);
    if (evenc && c > 0) stage_qhj(c >> 1);

    const ushort_t* bufc = (const ushort_t*)(smemc + (c & 1) * QT_PITCH_B);
    const ushort_t* qtH = bufc;
    const ushort_t* qtL = bufc + 16 * KP;

    // ---- pass 1 (attD chain split 12 -> 6 deep) ----
    f32x4 attD0 = {0, 0, 0, 0}, attD1 = {0, 0, 0, 0};
    f32x4 gaD = {0, 0, 0, 0}, gbD = {0, 0, 0, 0};
#pragma unroll
    for (int kt = 0; kt < 4; ++kt) {
      const int bo = li * KP + kt * 32 + 8 * lg;
      bf16x8 bHi = *(const bf16x8*)&qtH[bo];
      bf16x8 bLo = *(const bf16x8*)&qtL[bo];
      if ((kt & 1) == 0) {
        attD0 = __builtin_amdgcn_mfma_f32_16x16x32_bf16(pHi[kt], bHi, attD0, 0, 0, 0);
        attD0 = __builtin_amdgcn_mfma_f32_16x16x32_bf16(pLo[kt], bHi, attD0, 0, 0, 0);
        attD0 = __builtin_amdgcn_mfma_f32_16x16x32_bf16(pHi[kt], bLo, attD0, 0, 0, 0);
      } else {
        attD1 = __builtin_amdgcn_mfma_f32_16x16x32_bf16(pHi[kt], bHi, attD1, 0, 0, 0);
        attD1 = __builtin_amdgcn_mfma_f32_16x16x32_bf16(pLo[kt], bHi, attD1, 0, 0, 0);
        attD1 = __builtin_amdgcn_mfma_f32_16x16x32_bf16(pHi[kt], bLo, attD1, 0, 0, 0);
      }
      gaD = __builtin_amdgcn_mfma_f32_16x16x32_bf16(pGa[kt], bHi, gaD, 0, 0, 0);
      gbD = __builtin_amdgcn_mfma_f32_16x16x32_bf16(pGb[kt], bHi, gbD, 0, 0, 0);
    }
    {
      const int j = c * 16 + li;
      const float ra = nqs[j], rb = nqs[SS + j], rp = nqs[2 * SS + j];
#pragma unroll
      for (int r = 0; r < 4; ++r) {
        float d = (attD0[r] + attD1[r]) * rp;
        rowsum[r] += d;
        if (d > amax[r]) { amax[r] = d; aidx[r] = j; }
        m2a[r] = fmaxf(m2a[r], gaD[r] * ra);
        m2b[r] = fmaxf(m2b[r], gbD[r] * rb);
        bw[(lg * 4 + r) * BNCP + (c & 1) * 16 + li] = d;
      }
    }
    if (!evenc) {
      // ---- transpose-read 16x32 d, truncation hi/lo split ----
      asm volatile("s_waitcnt lgkmcnt(0)" ::: "memory");
      __builtin_amdgcn_sched_barrier(0);
      float4 v0 = *(const float4*)&bw[li * BNCP + lg * 8];
      float4 v1 = *(const float4*)&bw[li * BNCP + lg * 8 + 4];
      union { bf16x8 v; unsigned u[4]; } Hd, Ld;
      {
        float xf[8] = {v0.x, v0.y, v0.z, v0.w, v1.x, v1.y, v1.z, v1.w};
#pragma unroll
        for (int pr = 0; pr < 4; ++pr) {
          unsigned u0 = __float_as_uint(xf[2 * pr]);
          unsigned u1 = __float_as_uint(xf[2 * pr + 1]);
          Hd.u[pr] = (u0 >> 16) | (u1 & 0xFFFF0000u);
          float r0 = xf[2 * pr]     - __uint_as_float(u0 & 0xFFFF0000u);
          float r1 = xf[2 * pr + 1] - __uint_as_float(u1 & 0xFFFF0000u);
          Ld.u[pr] = (__float_as_uint(r0) >> 16) | (__float_as_uint(r1) & 0xFFFF0000u);
        }
      }
      // ---- pass 2 (per pair, K=32): hm += d * q^T, q hi only ----
#pragma unroll
      for (int nt = 0; nt < 7; ++nt) {
        const int ro = (nt * 16 + li) * QHJ_ROWP + lg * 8;
        bf16x8 qHi = *(const bf16x8*)&qjR[ro];
        hmD[nt] = __builtin_amdgcn_mfma_f32_16x16x32_bf16(Hd.v, qHi, hmD[nt], 0, 0, 0);
        hmD[nt] = __builtin_amdgcn_mfma_f32_16x16x32_bf16(Ld.v, qHi, hmD[nt], 0, 0, 0);
      }
    }
    __syncthreads();   // drains vmcnt (next stages landed) + all LDS reads done
  }

  // ---- stats reduce over li (rows are per-wave) ----
#pragma unroll
  for (int r = 0; r < 4; ++r) {
#pragma unroll
    for (int m = 1; m < 16; m <<= 1) {
      rowsum[r] += __shfl_xor(rowsum[r], m);
      float ov = __shfl_xor(amax[r], m);
      int   oi = __shfl_xor(aidx[r], m);
      if (ov > amax[r] || (ov == amax[r] && oi < aidx[r])) { amax[r] = ov; aidx[r] = oi; }
      m2a[r] = fmaxf(m2a[r], __shfl_xor(m2a[r], m));
      m2b[r] = fmaxf(m2b[r], __shfl_xor(m2b[r], m));
    }
  }
  if (li == 0) {
#pragma unroll
    for (int r = 0; r < 4; ++r) {
      const int row = lg * 4 + r;
      statb[((w * 16) + row) * 4 + 0] = (rowsum[r] < 0.f) ? -1.f : 1.f;
      statb[((w * 16) + row) * 4 + 1] = __int_as_float(aidx[r]);
      statb[((w * 16) + row) * 4 + 2] = m2a[r];
      statb[((w * 16) + row) * 4 + 3] = m2b[r];
    }
  }
  // hm to LDS (aliases chunk buffers; loop fully barriered out)
#pragma unroll
  for (int nt = 0; nt < 7; ++nt) {
#pragma unroll
    for (int r = 0; r < 4; ++r) {
      hmbuf[(size_t)(w * 16 + lg * 4 + r) * 116 + nt * 16 + li] = hmD[nt][r];
    }
  }
  __syncthreads();

  // ---- epilogue: 4 lanes per row, all 8 outputs ----
  {
    const int row = lane & 15, hq = lane >> 4;
    const int gi = rowbase + row;
    const float sg   = statb[((w * 16) + row) * 4 + 0];
    const int   ax   = __float_as_int(statb[((w * 16) + row) * 4 + 1]);
    const float m2av = statb[((w * 16) + row) * 4 + 2];
    const float m2bv = statb[((w * 16) + row) * 4 + 3];
    float ps0=0,ps1=0,ps2=0,ps3=0,ps4=0,ps5=0,ps6=0,ps7=0;
    float m1n0=0,m1n1=0,nq1a=0,nq1b=0;
    float m3n0=0,m3n1=0,nh0=0,nh1=0;
    float m4n0=0,m4n1=0,nq4a=0,nq4b=0;
#pragma unroll 5
    for (int k = 0; k < 25; ++k) {
      int h = k * 4 + hq;
      float pv = p[(size_t)h * BB * SS + (size_t)b * SS + gi];
      float hm = hmbuf[(size_t)(w * 16 + row) * 116 + h];
      float ql = qlast_s[h];
      float qi = q[(size_t)h * BB * SS + (size_t)b * SS + ax];
      float4 wv0 = *(const float4*)&wsq[h][0];
      float4 wv1 = *(const float4*)&wsq[h][4];
      float p2 = pv * pv;
      ps0 = fmaf(wv0.x, p2, ps0); ps1 = fmaf(wv0.y, p2, ps1);
      ps2 = fmaf(wv0.z, p2, ps2); ps3 = fmaf(wv0.w, p2, ps3);
      ps4 = fmaf(wv1.x, p2, ps4); ps5 = fmaf(wv1.y, p2, ps5);
      ps6 = fmaf(wv1.z, p2, ps6); ps7 = fmaf(wv1.w, p2, ps7);
      m1n0 = fmaf(wv0.x, pv * ql, m1n0); m1n1 = fmaf(wv0.y, pv * ql, m1n1);
      nq1a = fmaf(wv0.x, ql * ql, nq1a); nq1b = fmaf(wv0.y, ql * ql, nq1b);
      m3n0 = fmaf(wv1.x, pv * hm, m3n0); m3n1 = fmaf(wv1.y, pv * hm, m3n1);
      nh0  = fmaf(wv1.x, hm * hm, nh0);  nh1  = fmaf(wv1.y, hm * hm, nh1);
      m4n0 = fmaf(wv1.z, pv * qi, m4n0); m4n1 = fmaf(wv1.w, pv * qi, m4n1);
      nq4a = fmaf(wv1.z, qi * qi, nq4a); nq4b = fmaf(wv1.w, qi * qi, nq4b);
    }
#pragma unroll
    for (int m = 16; m < 64; m <<= 1) {
      ps0 += __shfl_xor(ps0, m);  ps1 += __shfl_xor(ps1, m);
      ps2 += __shfl_xor(ps2, m);  ps3 += __shfl_xor(ps3, m);
      ps4 += __shfl_xor(ps4, m);  ps5 += __shfl_xor(ps5, m);
      ps6 += __shfl_xor(ps6, m);  ps7 += __shfl_xor(ps7, m);
      m1n0 += __shfl_xor(m1n0, m); m1n1 += __shfl_xor(m1n1, m);
      nq1a += __shfl_xor(nq1a, m); nq1b += __shfl_xor(nq1b, m);
      m3n0 += __shfl_xor(m3n0, m); m3n1 += __shfl_xor(m3n1, m);
      nh0  += __shfl_xor(nh0,  m); nh1  += __shfl_xor(nh1,  m);
      m4n0 += __shfl_xor(m4n0, m); m4n1 += __shfl_xor(m4n1, m);
      nq4a += __shfl_xor(nq4a, m); nq4b += __shfl_xor(nq4b, m);
    }
    if (hq == 0) {
      const size_t base = (size_t)gi * (BB * 2) + (size_t)b * 2;
      out[(size_t)(0 + dir) * AS + base + 0] =
          m1n0 / (fmaxf(sqrtf(ps0), EPSF) * fmaxf(sqrtf(nq1a), EPSF));
      out[(size_t)(0 + dir) * AS + base + 1] =
          m1n1 / (fmaxf(sqrtf(ps1), EPSF) * fmaxf(sqrtf(nq1b), EPSF));
      out[(size_t)(2 + dir) * AS + base + 0] = m2av / fmaxf(sqrtf(ps2), EPSF);
      out[(size_t)(2 + dir) * AS + base + 1] = m2bv / fmaxf(sqrtf(ps3), EPSF);
      out[(size_t)(4 + dir) * AS + base + 0] =
          sg * m3n0 / (fmaxf(sqrtf(ps4), EPSF) * fmaxf(sqrtf(nh0), EPSF));
      out[(size_t)(4 + dir) * AS + base + 1] =
          sg * m3n1 / (fmaxf(sqrtf(ps5), EPSF) * fmaxf(sqrtf(nh1), EPSF));
      out[(size_t)(6 + dir) * AS + base + 0] =
          m4n0 / (fmaxf(sqrtf(ps6), EPSF) * fmaxf(sqrtf(nq4a), EPSF));
      out[(size_t)(6 + dir) * AS + base + 1] =
          m4n1 / (fmaxf(sqrtf(ps7), EPSF) * fmaxf(sqrtf(nq4b), EPSF));
    }
  }
}

extern "C" void kernel_launch(void* const* d_in, const int* in_sizes, int n_in,
                              void* d_out, int out_size, void* d_ws, size_t ws_size,
                              hipStream_t stream) {
  const float* pf  = (const float*)d_in[0];
  const float* pb  = (const float*)d_in[1];
  const float* qf  = (const float*)d_in[2];
  const float* qb  = (const float*)d_in[3];
  const float* w1f = (const float*)d_in[4];
  const float* w1b = (const float*)d_in[5];
  const float* w2f = (const float*)d_in[6];
  const float* w2b = (const float*)d_in[7];
  const float* w3f = (const float*)d_in[8];
  const float* w4f = (const float*)d_in[10];  // w3b/w4b unused by reference
  float* out = (float*)d_out;

  const size_t nq2_b  = (size_t)6 * BB * SS * 4;            //    589,824
  const size_t qhj_b  = (size_t)2 * HP * BB * SS * 2;       // 11,010,048
  float*    nq2    = (float*)d_ws;
  ushort_t* qhj_hi = (ushort_t*)((char*)d_ws + nq2_b);
  ushort_t* qTil   = (ushort_t*)((char*)d_ws + nq2_b + qhj_b);  // 26,738,688 B

  hipLaunchKernelGGL(qprep_kernel, dim3(2 * BB * 6), dim3(256), 0, stream,
                     qf, qb, w2f, w2b, nq2, qhj_hi, qTil);
  hipLaunchKernelGGL(bimpm_fused, dim3(2 * BB * 6), dim3(256), 0, stream,
                     pf, pb, qf, qb, w1f, w1b, w2f, w2b, w3f, w4f,
                     nq2, qhj_hi, qTil, out);
}

// Round 16
// 74.418 us; speedup vs baseline: 1.0314x; 1.0314x over previous
//
#include <hip/hip_runtime.h>
#include <math.h>

#define HH 100
#define HP 112
#define KP 136
#define BB 64
#define SS 384
#define EPSF 1e-6f
#define NCH 24                  // 16-j chunks; pass2 per pair (K=32)
#define QT16 4352               // ush per 16-j qT chunk (hi 16*KP | lo 16*KP) = 544 slots
#define QT_PITCH_B 9216         // qT buffer pitch (576 slots)
#define QHJ_OFF_B 18432         // qhj region offset (after 2 qT buffers)
#define QHJ_ROWP 40             // ush per qhj row (32 hi + 8 dup) = 5 slots
#define BNC_OFF_B 27392         // bounce offset
#define BNCP 36                 // bounce pitch (floats)
#define STATB_OFF_B 29696       // statb alias after loop
#define SMEM_B 36608

typedef __attribute__((ext_vector_type(8))) short bf16x8;
typedef __attribute__((ext_vector_type(4))) float f32x4;
typedef unsigned short ushort_t;

__device__ __forceinline__ ushort_t f2bf(float x) {
  unsigned u = __float_as_uint(x);
  unsigned r = (u + 0x7FFFu + ((u >> 16) & 1u)) >> 16;
  return (ushort_t)r;
}
__device__ __forceinline__ float bf2f(ushort_t h) {
  return __uint_as_float(((unsigned)h) << 16);
}
__device__ __forceinline__ void ld_g2l16(void* lds, const void* g) {
  __builtin_amdgcn_global_load_lds(
      (const __attribute__((address_space(1))) unsigned*)g,
      (__attribute__((address_space(3))) unsigned*)lds, 16, 0, 0);
}

// ---------------- Prep kernel: norms + qhj hi + 16j qT chunks ----------------
__global__ __launch_bounds__(256) void qprep_kernel(
    const float* __restrict__ qf, const float* __restrict__ qb,
    const float* __restrict__ w2f, const float* __restrict__ w2b,
    float* __restrict__ nq2, ushort_t* __restrict__ qhj_hi,
    ushort_t* __restrict__ qTil)
{
  __shared__ __align__(16) float tile[HH * 68];
  __shared__ float w2sq_s[HH][2];
  const int blk = blockIdx.x;
  const int dir = blk / (BB * 6);
  const int rem = blk % (BB * 6);
  const int b   = rem / 6;
  const int jt  = rem % 6;
  const int j0  = jt * 64;
  const float* q  = dir ? qb : qf;
  const float* w2 = dir ? w2b : w2f;
  const int t = threadIdx.x;
  if (t < HH) {
    float a = w2[t], c = w2[HH + t];
    w2sq_s[t][0] = a * a; w2sq_s[t][1] = c * c;
  }
  for (int e = t; e < HH * 16; e += 256) {
    int h = e >> 4, j4 = e & 15;
    float4 v = *(const float4*)&q[((size_t)h * BB + b) * SS + j0 + j4 * 4];
    *(float4*)&tile[h * 68 + j4 * 4] = v;
  }
  __syncthreads();
  // qT 16j-chunk-interleaved: [dir][b][chunk16][hi 16xKP | lo 16xKP]
  for (int e = t; e < 64 * KP; e += 256) {
    int jj = e / KP, kp = e % KP;
    float x = (kp < HH) ? tile[kp * 68 + jj] : 0.f;
    ushort_t hi = f2bf(x);
    int cg = jt * 4 + (jj >> 4);
    size_t base = ((size_t)(dir * BB + b) * NCH + cg) * QT16
                + (size_t)(jj & 15) * KP + kp;
    qTil[base] = hi;
    qTil[base + 16 * KP] = f2bf(x - bf2f(hi));
  }
  // qhj hi only (RNE), zero-padded h in [100,112)
  for (int e = t; e < HP * 64; e += 256) {
    int hp = e >> 6, jj = e & 63;
    float x = (hp < HH) ? tile[hp * 68 + jj] : 0.f;
    size_t o = ((size_t)(dir * HP + hp) * BB + b) * SS + j0 + jj;
    qhj_hi[o] = f2bf(x);
  }
  // reciprocal norms
  if (t < 64) {
    float s0 = 0.f, s1 = 0.f, sp = 0.f;
    for (int h = 0; h < HH; ++h) {
      float v = tile[h * 68 + t];
      float v2 = v * v;
      s0 = fmaf(w2sq_s[h][0], v2, s0);
      s1 = fmaf(w2sq_s[h][1], v2, s1);
      sp += v2;
    }
    int j = j0 + t;
    nq2[((size_t)(dir * 2 + 0) * BB + b) * SS + j] = 1.0f / fmaxf(sqrtf(s0), EPSF);
    nq2[((size_t)(dir * 2 + 1) * BB + b) * SS + j] = 1.0f / fmaxf(sqrtf(s1), EPSF);
    nq2[((size_t)(4 + dir) * BB + b) * SS + j]     = 1.0f / fmaxf(sqrtf(sp), EPSF);
  }
}

// ---------------- Main fused kernel: paired 16-j chunks ----------------
// __launch_bounds__(256, 3): (256,4) spilled hmD to scratch in R11 (2.2x
// slower). (256,3) compiles spill-free at 84-88 VGPR.
__global__ __launch_bounds__(256, 3) void bimpm_fused(
    const float* __restrict__ pf, const float* __restrict__ pb,
    const float* __restrict__ qf, const float* __restrict__ qb,
    const float* __restrict__ w1f, const float* __restrict__ w1b,
    const float* __restrict__ w2f, const float* __restrict__ w2b,
    const float* __restrict__ w3f_, const float* __restrict__ w4f_,
    const float* __restrict__ nq2ws,
    const ushort_t* __restrict__ qhj_hi, const ushort_t* __restrict__ qTil,
    float* __restrict__ out)
{
  __shared__ __align__(16) char smemc[SMEM_B];   // qT dbuf | qhj | bounce
  __shared__ __align__(16) float wsq[HH][8];     // 3200 B
  __shared__ float qlast_s[HH];                  // 400 B

  float* hmbuf = (float*)smemc;                  // [64][116] after loop
  float* statb = (float*)(smemc + STATB_OFF_B);  // [4][16][4] after loop
  float* bounce = (float*)(smemc + BNC_OFF_B);

  // XCD-aware work swizzle: 768 = 8 * 96, bijective
  const int bid  = blockIdx.x;
  const int work = (bid & 7) * 96 + (bid >> 3);
  const int dir = work / (BB * 6);
  const int rem = work % (BB * 6);
  const int b   = rem / 6;
  const int i0  = (rem % 6) * 64;

  const float* __restrict__ p  = dir ? pb : pf;
  const float* __restrict__ q  = dir ? qb : qf;
  const float* __restrict__ w1 = dir ? w1b : w1f;
  const float* __restrict__ w2 = dir ? w2b : w2f;
  const int t = threadIdx.x;
  const int w = t >> 6, lane = t & 63, li = lane & 15, lg = lane >> 4;
  const int rowbase = i0 + w * 16;
  const size_t AS = (size_t)SS * BB * 2;
  const size_t qt_base = (size_t)(dir * BB + b) * NCH * QT16;
  const ushort_t* __restrict__ qhjH0 = qhj_hi + ((size_t)dir * HP * BB + b) * SS;

  if (t < HH) {
    float a, c;
    a = w1[t];   c = w1[HH + t];   wsq[t][0] = a*a; wsq[t][1] = c*c;
    a = w2[t];   c = w2[HH + t];   wsq[t][2] = a*a; wsq[t][3] = c*c;
    a = w3f_[t]; c = w3f_[HH + t]; wsq[t][4] = a*a; wsq[t][5] = c*c;
    a = w4f_[t]; c = w4f_[HH + t]; wsq[t][6] = a*a; wsq[t][7] = c*c;
    qlast_s[t] = q[(size_t)t * BB * SS + (size_t)b * SS + (SS - 1)];
  }

  // ---- async qT chunk stage: 544 slots linear ----
  auto stage_qt = [&](int cc, int bi) {
    char* dst = smemc + bi * QT_PITCH_B;
    const char* gsrc = (const char*)(qTil + qt_base + (size_t)cc * QT16);
#pragma unroll
    for (int k = 0; k < 2; ++k) {
      const int sb = k * 256 + w * 64;
      ld_g2l16(dst + (size_t)sb * 16, gsrc + (size_t)(sb + lane) * 16);
    }
    if (w == 0 && lane < 32)
      ld_g2l16(dst + (size_t)512 * 16, gsrc + (size_t)(512 + lane) * 16);
  };
  // ---- async qhj stage for pair P ----
  // SCHEDULE: issued ONLY at the top of even chunk 2P (P=0 in prologue).
  // Pass-2 of pair P-1 finished before the barrier ending chunk 2P-1, so no
  // overwrite; the barrier ending chunk 2P drains vmcnt before pair P's reads
  // at the end of chunk 2P+1.
  auto stage_qhj = [&](int P) {
    char* dst = smemc + QHJ_OFF_B;
#pragma unroll
    for (int k = 0; k < 3; ++k) {
      const int sb = k * 256 + w * 64;
      if (k < 2 || (w == 0 && lane < 48)) {
        int v = sb + lane;
        int hp = v / 5;
        int s = v - hp * 5;
        if (s == 4) s = 0;   // dup pad slot
        const ushort_t* src = qhjH0 + (size_t)hp * (BB * SS) + P * 32 + s * 8;
        ld_g2l16(dst + (size_t)sb * 16, src);
      }
    }
  };

  stage_qt(0, 0);
  stage_qhj(0);

  // ---- p fragments in registers ----
  bf16x8 pHi[4], pLo[4], pGa[4], pGb[4];
#pragma unroll
  for (int kt = 0; kt < 4; ++kt) {
#pragma unroll
    for (int s = 0; s < 8; ++s) {
      int h = kt * 32 + 8 * lg + s;
      float pv = 0.f, ga = 0.f, gb = 0.f;
      if (h < HH) {
        pv = p[(size_t)h * BB * SS + (size_t)b * SS + rowbase + li];
        float wa = w2[h], wb = w2[HH + h];
        ga = pv * wa * wa;
        gb = pv * wb * wb;
      }
      ushort_t hi = f2bf(pv);
      pHi[kt][s] = (short)hi;
      pLo[kt][s] = (short)f2bf(pv - bf2f(hi));
      pGa[kt][s] = (short)f2bf(ga);
      pGb[kt][s] = (short)f2bf(gb);
    }
  }
  __syncthreads();   // buf0 + qhj(0) staged

  f32x4 hmD[7];
#pragma unroll
  for (int nt = 0; nt < 7; ++nt) hmD[nt] = (f32x4){0.f, 0.f, 0.f, 0.f};
  float rowsum[4] = {0, 0, 0, 0};
  float amax[4] = {-INFINITY, -INFINITY, -INFINITY, -INFINITY};
  float m2a[4] = {-INFINITY, -INFINITY, -INFINITY, -INFINITY};
  float m2b[4] = {-INFINITY, -INFINITY, -INFINITY, -INFINITY};
  int aidx[4] = {0, 0, 0, 0};
  const float* nqa = nq2ws + ((size_t)(dir * 2 + 0) * BB + b) * SS;
  const float* nqb = nq2ws + ((size_t)(dir * 2 + 1) * BB + b) * SS;
  const float* nqp = nq2ws + ((size_t)(4 + dir) * BB + b) * SS;
  float* bw = bounce + w * (16 * BNCP);
  const ushort_t* qjR = (const ushort_t*)(smemc + QHJ_OFF_B);

  for (int c = 0; c < NCH; ++c) {
    const bool evenc = (c & 1) == 0;
    if (c + 1 < NCH) stage_qt(c + 1, (c + 1) & 1);
    if (evenc && c > 0) stage_qhj(c >> 1);

    const ushort_t* bufc = (const ushort_t*)(smemc + (c & 1) * QT_PITCH_B);
    const ushort_t* qtH = bufc;
    const ushort_t* qtL = bufc + 16 * KP;

    // ---- pass 1 (attD chain split 12 -> 6 deep) ----
    f32x4 attD0 = {0, 0, 0, 0}, attD1 = {0, 0, 0, 0};
    f32x4 gaD = {0, 0, 0, 0}, gbD = {0, 0, 0, 0};
#pragma unroll
    for (int kt = 0; kt < 4; ++kt) {
      const int bo = li * KP + kt * 32 + 8 * lg;
      bf16x8 bHi = *(const bf16x8*)&qtH[bo];
      bf16x8 bLo = *(const bf16x8*)&qtL[bo];
      if ((kt & 1) == 0) {
        attD0 = __builtin_amdgcn_mfma_f32_16x16x32_bf16(pHi[kt], bHi, attD0, 0, 0, 0);
        attD0 = __builtin_amdgcn_mfma_f32_16x16x32_bf16(pLo[kt], bHi, attD0, 0, 0, 0);
        attD0 = __builtin_amdgcn_mfma_f32_16x16x32_bf16(pHi[kt], bLo, attD0, 0, 0, 0);
      } else {
        attD1 = __builtin_amdgcn_mfma_f32_16x16x32_bf16(pHi[kt], bHi, attD1, 0, 0, 0);
        attD1 = __builtin_amdgcn_mfma_f32_16x16x32_bf16(pLo[kt], bHi, attD1, 0, 0, 0);
        attD1 = __builtin_amdgcn_mfma_f32_16x16x32_bf16(pHi[kt], bLo, attD1, 0, 0, 0);
      }
      gaD = __builtin_amdgcn_mfma_f32_16x16x32_bf16(pGa[kt], bHi, gaD, 0, 0, 0);
      gbD = __builtin_amdgcn_mfma_f32_16x16x32_bf16(pGb[kt], bHi, gbD, 0, 0, 0);
    }
    {
      const int j = c * 16 + li;
      const float rp = nqp[j], ra = nqa[j], rb = nqb[j];
#pragma unroll
      for (int r = 0; r < 4; ++r) {
        float d = (attD0[r] + attD1[r]) * rp;
        rowsum[r] += d;
        if (d > amax[r]) { amax[r] = d; aidx[r] = j; }
        m2a[r] = fmaxf(m2a[r], gaD[r] * ra);
        m2b[r] = fmaxf(m2b[r], gbD[r] * rb);
        bw[(lg * 4 + r) * BNCP + (c & 1) * 16 + li] = d;
      }
    }
    if (!evenc) {
      // ---- transpose-read 16x32 d, RNE bf16 (single term; q-hi + d-RNE
      // leave hm rel err ~2^-9, which largely cancels in the m3 cosine) ----
      asm volatile("s_waitcnt lgkmcnt(0)" ::: "memory");
      __builtin_amdgcn_sched_barrier(0);
      float4 v0 = *(const float4*)&bw[li * BNCP + lg * 8];
      float4 v1 = *(const float4*)&bw[li * BNCP + lg * 8 + 4];
      bf16x8 Hd;
      {
        float xf[8] = {v0.x, v0.y, v0.z, v0.w, v1.x, v1.y, v1.z, v1.w};
#pragma unroll
        for (int s = 0; s < 8; ++s) Hd[s] = (short)f2bf(xf[s]);
      }
      // ---- pass 2 (per pair, K=32): hm += d * q^T ----
#pragma unroll
      for (int nt = 0; nt < 7; ++nt) {
        const int ro = (nt * 16 + li) * QHJ_ROWP + lg * 8;
        bf16x8 qHi = *(const bf16x8*)&qjR[ro];
        hmD[nt] = __builtin_amdgcn_mfma_f32_16x16x32_bf16(Hd, qHi, hmD[nt], 0, 0, 0);
      }
    }
    __syncthreads();   // drains vmcnt (next stages landed) + all LDS reads done
  }

  // ---- stats reduce over li (rows are per-wave) ----
#pragma unroll
  for (int r = 0; r < 4; ++r) {
#pragma unroll
    for (int m = 1; m < 16; m <<= 1) {
      rowsum[r] += __shfl_xor(rowsum[r], m);
      float ov = __shfl_xor(amax[r], m);
      int   oi = __shfl_xor(aidx[r], m);
      if (ov > amax[r] || (ov == amax[r] && oi < aidx[r])) { amax[r] = ov; aidx[r] = oi; }
      m2a[r] = fmaxf(m2a[r], __shfl_xor(m2a[r], m));
      m2b[r] = fmaxf(m2b[r], __shfl_xor(m2b[r], m));
    }
  }
  if (li == 0) {
#pragma unroll
    for (int r = 0; r < 4; ++r) {
      const int row = lg * 4 + r;
      statb[((w * 16) + row) * 4 + 0] = (rowsum[r] < 0.f) ? -1.f : 1.f;
      statb[((w * 16) + row) * 4 + 1] = __int_as_float(aidx[r]);
      statb[((w * 16) + row) * 4 + 2] = m2a[r];
      statb[((w * 16) + row) * 4 + 3] = m2b[r];
    }
  }
  // hm to LDS (aliases chunk buffers; loop fully barriered out)
#pragma unroll
  for (int nt = 0; nt < 7; ++nt) {
#pragma unroll
    for (int r = 0; r < 4; ++r) {
      hmbuf[(size_t)(w * 16 + lg * 4 + r) * 116 + nt * 16 + li] = hmD[nt][r];
    }
  }
  __syncthreads();

  // ---- epilogue: 4 lanes per row, all 8 outputs ----
  {
    const int row = lane & 15, hq = lane >> 4;
    const int gi = rowbase + row;
    const float sg   = statb[((w * 16) + row) * 4 + 0];
    const int   ax   = __float_as_int(statb[((w * 16) + row) * 4 + 1]);
    const float m2av = statb[((w * 16) + row) * 4 + 2];
    const float m2bv = statb[((w * 16) + row) * 4 + 3];
    float ps0=0,ps1=0,ps2=0,ps3=0,ps4=0,ps5=0,ps6=0,ps7=0;
    float m1n0=0,m1n1=0,nq1a=0,nq1b=0;
    float m3n0=0,m3n1=0,nh0=0,nh1=0;
    float m4n0=0,m4n1=0,nq4a=0,nq4b=0;
#pragma unroll 5
    for (int k = 0; k < 25; ++k) {
      int h = k * 4 + hq;
      float pv = p[(size_t)h * BB * SS + (size_t)b * SS + gi];
      float hm = hmbuf[(size_t)(w * 16 + row) * 116 + h];
      float ql = qlast_s[h];
      float qi = q[(size_t)h * BB * SS + (size_t)b * SS + ax];
      float4 wv0 = *(const float4*)&wsq[h][0];
      float4 wv1 = *(const float4*)&wsq[h][4];
      float p2 = pv * pv;
      ps0 = fmaf(wv0.x, p2, ps0); ps1 = fmaf(wv0.y, p2, ps1);
      ps2 = fmaf(wv0.z, p2, ps2); ps3 = fmaf(wv0.w, p2, ps3);
      ps4 = fmaf(wv1.x, p2, ps4); ps5 = fmaf(wv1.y, p2, ps5);
      ps6 = fmaf(wv1.z, p2, ps6); ps7 = fmaf(wv1.w, p2, ps7);
      m1n0 = fmaf(wv0.x, pv * ql, m1n0); m1n1 = fmaf(wv0.y, pv * ql, m1n1);
      nq1a = fmaf(wv0.x, ql * ql, nq1a); nq1b = fmaf(wv0.y, ql * ql, nq1b);
      m3n0 = fmaf(wv1.x, pv * hm, m3n0); m3n1 = fmaf(wv1.y, pv * hm, m3n1);
      nh0  = fmaf(wv1.x, hm * hm, nh0);  nh1  = fmaf(wv1.y, hm * hm, nh1);
      m4n0 = fmaf(wv1.z, pv * qi, m4n0); m4n1 = fmaf(wv1.w, pv * qi, m4n1);
      nq4a = fmaf(wv1.z, qi * qi, nq4a); nq4b = fmaf(wv1.w, qi * qi, nq4b);
    }
#pragma unroll
    for (int m = 16; m < 64; m <<= 1) {
      ps0 += __shfl_xor(ps0, m);  ps1 += __shfl_xor(ps1, m);
      ps2 += __shfl_xor(ps2, m);  ps3 += __shfl_xor(ps3, m);
      ps4 += __shfl_xor(ps4, m);  ps5 += __shfl_xor(ps5, m);
      ps6 += __shfl_xor(ps6, m);  ps7 += __shfl_xor(ps7, m);
      m1n0 += __shfl_xor(m1n0, m); m1n1 += __shfl_xor(m1n1, m);
      nq1a += __shfl_xor(nq1a, m); nq1b += __shfl_xor(nq1b, m);
      m3n0 += __shfl_xor(m3n0, m); m3n1 += __shfl_xor(m3n1, m);
      nh0  += __shfl_xor(nh0,  m); nh1  += __shfl_xor(nh1,  m);
      m4n0 += __shfl_xor(m4n0, m); m4n1 += __shfl_xor(m4n1, m);
      nq4a += __shfl_xor(nq4a, m); nq4b += __shfl_xor(nq4b, m);
    }
    if (hq == 0) {
      const size_t base = (size_t)gi * (BB * 2) + (size_t)b * 2;
      out[(size_t)(0 + dir) * AS + base + 0] =
          m1n0 / (fmaxf(sqrtf(ps0), EPSF) * fmaxf(sqrtf(nq1a), EPSF));
      out[(size_t)(0 + dir) * AS + base + 1] =
          m1n1 / (fmaxf(sqrtf(ps1), EPSF) * fmaxf(sqrtf(nq1b), EPSF));
      out[(size_t)(2 + dir) * AS + base + 0] = m2av / fmaxf(sqrtf(ps2), EPSF);
      out[(size_t)(2 + dir) * AS + base + 1] = m2bv / fmaxf(sqrtf(ps3), EPSF);
      out[(size_t)(4 + dir) * AS + base + 0] =
          sg * m3n0 / (fmaxf(sqrtf(ps4), EPSF) * fmaxf(sqrtf(nh0), EPSF));
      out[(size_t)(4 + dir) * AS + base + 1] =
          sg * m3n1 / (fmaxf(sqrtf(ps5), EPSF) * fmaxf(sqrtf(nh1), EPSF));
      out[(size_t)(6 + dir) * AS + base + 0] =
          m4n0 / (fmaxf(sqrtf(ps6), EPSF) * fmaxf(sqrtf(nq4a), EPSF));
      out[(size_t)(6 + dir) * AS + base + 1] =
          m4n1 / (fmaxf(sqrtf(ps7), EPSF) * fmaxf(sqrtf(nq4b), EPSF));
    }
  }
}

extern "C" void kernel_launch(void* const* d_in, const int* in_sizes, int n_in,
                              void* d_out, int out_size, void* d_ws, size_t ws_size,
                              hipStream_t stream) {
  const float* pf  = (const float*)d_in[0];
  const float* pb  = (const float*)d_in[1];
  const float* qf  = (const float*)d_in[2];
  const float* qb  = (const float*)d_in[3];
  const float* w1f = (const float*)d_in[4];
  const float* w1b = (const float*)d_in[5];
  const float* w2f = (const float*)d_in[6];
  const float* w2b = (const float*)d_in[7];
  const float* w3f = (const float*)d_in[8];
  const float* w4f = (const float*)d_in[10];  // w3b/w4b unused by reference
  float* out = (float*)d_out;

  const size_t nq2_b  = (size_t)6 * BB * SS * 4;            //    589,824
  const size_t qhj_b  = (size_t)2 * HP * BB * SS * 2;       // 11,010,048
  float*    nq2    = (float*)d_ws;
  ushort_t* qhj_hi = (ushort_t*)((char*)d_ws + nq2_b);
  ushort_t* qTil   = (ushort_t*)((char*)d_ws + nq2_b + qhj_b);  // 26,738,688 B

  hipLaunchKernelGGL(qprep_kernel, dim3(2 * BB * 6), dim3(256), 0, stream,
                     qf, qb, w2f, w2b, nq2, qhj_hi, qTil);
  hipLaunchKernelGGL(bimpm_fused, dim3(2 * BB * 6), dim3(256), 0, stream,
                     pf, pb, qf, qb, w1f, w1b, w2f, w2b, w3f, w4f,
                     nq2, qhj_hi, qTil, out);
}

// Round 17
// 73.362 us; speedup vs baseline: 1.0463x; 1.0144x over previous
//
#include <hip/hip_runtime.h>
#include <math.h>

#define HH 100
#define HP 112
#define KP 136
#define BB 64
#define SS 384
#define EPSF 1e-6f
#define NCH 24                  // 16-j chunks; pass2 per pair (K=32)
#define QT16 4352               // ush per 16-j qT chunk (hi 16*KP | lo 16*KP) = 544 slots
#define QT_PITCH_B 9216         // qT buffer pitch (576 slots)
#define QHJ_OFF_B 18432         // qhj region offset (after 2 qT buffers)
#define QHJ_ROWP 40             // ush per qhj row (32 hi + 8 dup) = 5 slots
#define BNC_OFF_B 27392         // bounce offset
#define BNCP 36                 // bounce pitch (floats)
#define STATB_OFF_B 29696       // statb alias after loop
#define SMEM_B 36608

typedef __attribute__((ext_vector_type(8))) short bf16x8;
typedef __attribute__((ext_vector_type(4))) float f32x4;
typedef unsigned short ushort_t;

__device__ __forceinline__ ushort_t f2bf(float x) {
  unsigned u = __float_as_uint(x);
  unsigned r = (u + 0x7FFFu + ((u >> 16) & 1u)) >> 16;
  return (ushort_t)r;
}
__device__ __forceinline__ float bf2f(ushort_t h) {
  return __uint_as_float(((unsigned)h) << 16);
}
__device__ __forceinline__ void ld_g2l16(void* lds, const void* g) {
  __builtin_amdgcn_global_load_lds(
      (const __attribute__((address_space(1))) unsigned*)g,
      (__attribute__((address_space(3))) unsigned*)lds, 16, 0, 0);
}

// ---------------- Prep kernel: norms + qhj hi + 16j qT chunks ----------------
// XCD-ALIGNED (R17): decode work through the SAME swizzle as the main kernel,
// so the producer of slice (dir,b) runs on the XCD whose L2 the consumer
// blocks will read — prep's dirty L2 lines are local-warm for bimpm_fused.
__global__ __launch_bounds__(256) void qprep_kernel(
    const float* __restrict__ qf, const float* __restrict__ qb,
    const float* __restrict__ w2f, const float* __restrict__ w2b,
    float* __restrict__ nq2, ushort_t* __restrict__ qhj_hi,
    ushort_t* __restrict__ qTil)
{
  __shared__ __align__(16) float tile[HH * 68];
  __shared__ float w2sq_s[HH][2];
  const int bid  = blockIdx.x;
  const int work = (bid & 7) * 96 + (bid >> 3);   // bijective, 768 = 8*96
  const int dir = work / (BB * 6);
  const int rem = work % (BB * 6);
  const int b   = rem / 6;
  const int jt  = rem % 6;
  const int j0  = jt * 64;
  const float* q  = dir ? qb : qf;
  const float* w2 = dir ? w2b : w2f;
  const int t = threadIdx.x;
  if (t < HH) {
    float a = w2[t], c = w2[HH + t];
    w2sq_s[t][0] = a * a; w2sq_s[t][1] = c * c;
  }
  for (int e = t; e < HH * 16; e += 256) {
    int h = e >> 4, j4 = e & 15;
    float4 v = *(const float4*)&q[((size_t)h * BB + b) * SS + j0 + j4 * 4];
    *(float4*)&tile[h * 68 + j4 * 4] = v;
  }
  __syncthreads();
  // qT 16j-chunk-interleaved: [dir][b][chunk16][hi 16xKP | lo 16xKP]
  for (int e = t; e < 64 * KP; e += 256) {
    int jj = e / KP, kp = e % KP;
    float x = (kp < HH) ? tile[kp * 68 + jj] : 0.f;
    ushort_t hi = f2bf(x);
    int cg = jt * 4 + (jj >> 4);
    size_t base = ((size_t)(dir * BB + b) * NCH + cg) * QT16
                + (size_t)(jj & 15) * KP + kp;
    qTil[base] = hi;
    qTil[base + 16 * KP] = f2bf(x - bf2f(hi));
  }
  // qhj hi only (RNE), zero-padded h in [100,112)
  for (int e = t; e < HP * 64; e += 256) {
    int hp = e >> 6, jj = e & 63;
    float x = (hp < HH) ? tile[hp * 68 + jj] : 0.f;
    size_t o = ((size_t)(dir * HP + hp) * BB + b) * SS + j0 + jj;
    qhj_hi[o] = f2bf(x);
  }
  // reciprocal norms
  if (t < 64) {
    float s0 = 0.f, s1 = 0.f, sp = 0.f;
    for (int h = 0; h < HH; ++h) {
      float v = tile[h * 68 + t];
      float v2 = v * v;
      s0 = fmaf(w2sq_s[h][0], v2, s0);
      s1 = fmaf(w2sq_s[h][1], v2, s1);
      sp += v2;
    }
    int j = j0 + t;
    nq2[((size_t)(dir * 2 + 0) * BB + b) * SS + j] = 1.0f / fmaxf(sqrtf(s0), EPSF);
    nq2[((size_t)(dir * 2 + 1) * BB + b) * SS + j] = 1.0f / fmaxf(sqrtf(s1), EPSF);
    nq2[((size_t)(4 + dir) * BB + b) * SS + j]     = 1.0f / fmaxf(sqrtf(sp), EPSF);
  }
}

// ---------------- Main fused kernel: paired 16-j chunks ----------------
// __launch_bounds__(256, 3): (256,4) spilled hmD to scratch in R11 (2.2x
// slower). (256,3) compiles spill-free at 84-88 VGPR.
__global__ __launch_bounds__(256, 3) void bimpm_fused(
    const float* __restrict__ pf, const float* __restrict__ pb,
    const float* __restrict__ qf, const float* __restrict__ qb,
    const float* __restrict__ w1f, const float* __restrict__ w1b,
    const float* __restrict__ w2f, const float* __restrict__ w2b,
    const float* __restrict__ w3f_, const float* __restrict__ w4f_,
    const float* __restrict__ nq2ws,
    const ushort_t* __restrict__ qhj_hi, const ushort_t* __restrict__ qTil,
    float* __restrict__ out)
{
  __shared__ __align__(16) char smemc[SMEM_B];   // qT dbuf | qhj | bounce
  __shared__ __align__(16) float wsq[HH][8];     // 3200 B
  __shared__ float qlast_s[HH];                  // 400 B

  float* hmbuf = (float*)smemc;                  // [64][116] after loop
  float* statb = (float*)(smemc + STATB_OFF_B);  // [4][16][4] after loop
  float* bounce = (float*)(smemc + BNC_OFF_B);

  // XCD-aware work swizzle: 768 = 8 * 96, bijective
  const int bid  = blockIdx.x;
  const int work = (bid & 7) * 96 + (bid >> 3);
  const int dir = work / (BB * 6);
  const int rem = work % (BB * 6);
  const int b   = rem / 6;
  const int i0  = (rem % 6) * 64;

  const float* __restrict__ p  = dir ? pb : pf;
  const float* __restrict__ q  = dir ? qb : qf;
  const float* __restrict__ w1 = dir ? w1b : w1f;
  const float* __restrict__ w2 = dir ? w2b : w2f;
  const int t = threadIdx.x;
  const int w = t >> 6, lane = t & 63, li = lane & 15, lg = lane >> 4;
  const int rowbase = i0 + w * 16;
  const size_t AS = (size_t)SS * BB * 2;
  const size_t qt_base = (size_t)(dir * BB + b) * NCH * QT16;
  const ushort_t* __restrict__ qhjH0 = qhj_hi + ((size_t)dir * HP * BB + b) * SS;

  if (t < HH) {
    float a, c;
    a = w1[t];   c = w1[HH + t];   wsq[t][0] = a*a; wsq[t][1] = c*c;
    a = w2[t];   c = w2[HH + t];   wsq[t][2] = a*a; wsq[t][3] = c*c;
    a = w3f_[t]; c = w3f_[HH + t]; wsq[t][4] = a*a; wsq[t][5] = c*c;
    a = w4f_[t]; c = w4f_[HH + t]; wsq[t][6] = a*a; wsq[t][7] = c*c;
    qlast_s[t] = q[(size_t)t * BB * SS + (size_t)b * SS + (SS - 1)];
  }

  // ---- async qT chunk stage: 544 slots linear ----
  auto stage_qt = [&](int cc, int bi) {
    char* dst = smemc + bi * QT_PITCH_B;
    const char* gsrc = (const char*)(qTil + qt_base + (size_t)cc * QT16);
#pragma unroll
    for (int k = 0; k < 2; ++k) {
      const int sb = k * 256 + w * 64;
      ld_g2l16(dst + (size_t)sb * 16, gsrc + (size_t)(sb + lane) * 16);
    }
    if (w == 0 && lane < 32)
      ld_g2l16(dst + (size_t)512 * 16, gsrc + (size_t)(512 + lane) * 16);
  };
  // ---- async qhj stage for pair P ----
  // SCHEDULE: issued ONLY at the top of even chunk 2P (P=0 in prologue).
  // Pass-2 of pair P-1 finished before the barrier ending chunk 2P-1, so no
  // overwrite; the barrier ending chunk 2P drains vmcnt before pair P's reads
  // at the end of chunk 2P+1.
  auto stage_qhj = [&](int P) {
    char* dst = smemc + QHJ_OFF_B;
#pragma unroll
    for (int k = 0; k < 3; ++k) {
      const int sb = k * 256 + w * 64;
      if (k < 2 || (w == 0 && lane < 48)) {
        int v = sb + lane;
        int hp = v / 5;
        int s = v - hp * 5;
        if (s == 4) s = 0;   // dup pad slot
        const ushort_t* src = qhjH0 + (size_t)hp * (BB * SS) + P * 32 + s * 8;
        ld_g2l16(dst + (size_t)sb * 16, src);
      }
    }
  };

  stage_qt(0, 0);
  stage_qhj(0);

  // ---- p fragments in registers ----
  bf16x8 pHi[4], pLo[4], pGa[4], pGb[4];
#pragma unroll
  for (int kt = 0; kt < 4; ++kt) {
#pragma unroll
    for (int s = 0; s < 8; ++s) {
      int h = kt * 32 + 8 * lg + s;
      float pv = 0.f, ga = 0.f, gb = 0.f;
      if (h < HH) {
        pv = p[(size_t)h * BB * SS + (size_t)b * SS + rowbase + li];
        float wa = w2[h], wb = w2[HH + h];
        ga = pv * wa * wa;
        gb = pv * wb * wb;
      }
      ushort_t hi = f2bf(pv);
      pHi[kt][s] = (short)hi;
      pLo[kt][s] = (short)f2bf(pv - bf2f(hi));
      pGa[kt][s] = (short)f2bf(ga);
      pGb[kt][s] = (short)f2bf(gb);
    }
  }
  __syncthreads();   // buf0 + qhj(0) staged

  f32x4 hmD[7];
#pragma unroll
  for (int nt = 0; nt < 7; ++nt) hmD[nt] = (f32x4){0.f, 0.f, 0.f, 0.f};
  float rowsum[4] = {0, 0, 0, 0};
  float amax[4] = {-INFINITY, -INFINITY, -INFINITY, -INFINITY};
  float m2a[4] = {-INFINITY, -INFINITY, -INFINITY, -INFINITY};
  float m2b[4] = {-INFINITY, -INFINITY, -INFINITY, -INFINITY};
  int aidx[4] = {0, 0, 0, 0};
  const float* nqa = nq2ws + ((size_t)(dir * 2 + 0) * BB + b) * SS;
  const float* nqb = nq2ws + ((size_t)(dir * 2 + 1) * BB + b) * SS;
  const float* nqp = nq2ws + ((size_t)(4 + dir) * BB + b) * SS;
  float* bw = bounce + w * (16 * BNCP);
  const ushort_t* qjR = (const ushort_t*)(smemc + QHJ_OFF_B);

  for (int c = 0; c < NCH; ++c) {
    const bool evenc = (c & 1) == 0;
    if (c + 1 < NCH) stage_qt(c + 1, (c + 1) & 1);
    if (evenc && c > 0) stage_qhj(c >> 1);

    const ushort_t* bufc = (const ushort_t*)(smemc + (c & 1) * QT_PITCH_B);
    const ushort_t* qtH = bufc;
    const ushort_t* qtL = bufc + 16 * KP;

    // ---- pass 1 (attD chain split 12 -> 6 deep) ----
    f32x4 attD0 = {0, 0, 0, 0}, attD1 = {0, 0, 0, 0};
    f32x4 gaD = {0, 0, 0, 0}, gbD = {0, 0, 0, 0};
#pragma unroll
    for (int kt = 0; kt < 4; ++kt) {
      const int bo = li * KP + kt * 32 + 8 * lg;
      bf16x8 bHi = *(const bf16x8*)&qtH[bo];
      bf16x8 bLo = *(const bf16x8*)&qtL[bo];
      if ((kt & 1) == 0) {
        attD0 = __builtin_amdgcn_mfma_f32_16x16x32_bf16(pHi[kt], bHi, attD0, 0, 0, 0);
        attD0 = __builtin_amdgcn_mfma_f32_16x16x32_bf16(pLo[kt], bHi, attD0, 0, 0, 0);
        attD0 = __builtin_amdgcn_mfma_f32_16x16x32_bf16(pHi[kt], bLo, attD0, 0, 0, 0);
      } else {
        attD1 = __builtin_amdgcn_mfma_f32_16x16x32_bf16(pHi[kt], bHi, attD1, 0, 0, 0);
        attD1 = __builtin_amdgcn_mfma_f32_16x16x32_bf16(pLo[kt], bHi, attD1, 0, 0, 0);
        attD1 = __builtin_amdgcn_mfma_f32_16x16x32_bf16(pHi[kt], bLo, attD1, 0, 0, 0);
      }
      gaD = __builtin_amdgcn_mfma_f32_16x16x32_bf16(pGa[kt], bHi, gaD, 0, 0, 0);
      gbD = __builtin_amdgcn_mfma_f32_16x16x32_bf16(pGb[kt], bHi, gbD, 0, 0, 0);
    }
    {
      const int j = c * 16 + li;
      const float rp = nqp[j], ra = nqa[j], rb = nqb[j];
#pragma unroll
      for (int r = 0; r < 4; ++r) {
        float d = (attD0[r] + attD1[r]) * rp;
        rowsum[r] += d;
        if (d > amax[r]) { amax[r] = d; aidx[r] = j; }
        m2a[r] = fmaxf(m2a[r], gaD[r] * ra);
        m2b[r] = fmaxf(m2b[r], gbD[r] * rb);
        bw[(lg * 4 + r) * BNCP + (c & 1) * 16 + li] = d;
      }
    }
    if (!evenc) {
      // ---- transpose-read 16x32 d, RNE bf16 (single term; q-hi + d-RNE
      // leave hm rel err ~2^-9, which largely cancels in the m3 cosine) ----
      asm volatile("s_waitcnt lgkmcnt(0)" ::: "memory");
      __builtin_amdgcn_sched_barrier(0);
      float4 v0 = *(const float4*)&bw[li * BNCP + lg * 8];
      float4 v1 = *(const float4*)&bw[li * BNCP + lg * 8 + 4];
      bf16x8 Hd;
      {
        float xf[8] = {v0.x, v0.y, v0.z, v0.w, v1.x, v1.y, v1.z, v1.w};
#pragma unroll
        for (int s = 0; s < 8; ++s) Hd[s] = (short)f2bf(xf[s]);
      }
      // ---- pass 2 (per pair, K=32): hm += d * q^T ----
#pragma unroll
      for (int nt = 0; nt < 7; ++nt) {
        const int ro = (nt * 16 + li) * QHJ_ROWP + lg * 8;
        bf16x8 qHi = *(const bf16x8*)&qjR[ro];
        hmD[nt] = __builtin_amdgcn_mfma_f32_16x16x32_bf16(Hd, qHi, hmD[nt], 0, 0, 0);
      }
    }
    __syncthreads();   // drains vmcnt (next stages landed) + all LDS reads done
  }

  // ---- stats reduce over li (rows are per-wave) ----
#pragma unroll
  for (int r = 0; r < 4; ++r) {
#pragma unroll
    for (int m = 1; m < 16; m <<= 1) {
      rowsum[r] += __shfl_xor(rowsum[r], m);
      float ov = __shfl_xor(amax[r], m);
      int   oi = __shfl_xor(aidx[r], m);
      if (ov > amax[r] || (ov == amax[r] && oi < aidx[r])) { amax[r] = ov; aidx[r] = oi; }
      m2a[r] = fmaxf(m2a[r], __shfl_xor(m2a[r], m));
      m2b[r] = fmaxf(m2b[r], __shfl_xor(m2b[r], m));
    }
  }
  if (li == 0) {
#pragma unroll
    for (int r = 0; r < 4; ++r) {
      const int row = lg * 4 + r;
      statb[((w * 16) + row) * 4 + 0] = (rowsum[r] < 0.f) ? -1.f : 1.f;
      statb[((w * 16) + row) * 4 + 1] = __int_as_float(aidx[r]);
      statb[((w * 16) + row) * 4 + 2] = m2a[r];
      statb[((w * 16) + row) * 4 + 3] = m2b[r];
    }
  }
  // hm to LDS (aliases chunk buffers; loop fully barriered out)
#pragma unroll
  for (int nt = 0; nt < 7; ++nt) {
#pragma unroll
    for (int r = 0; r < 4; ++r) {
      hmbuf[(size_t)(w * 16 + lg * 4 + r) * 116 + nt * 16 + li] = hmD[nt][r];
    }
  }
  __syncthreads();

  // ---- epilogue: 4 lanes per row, all 8 outputs ----
  {
    const int row = lane & 15, hq = lane >> 4;
    const int gi = rowbase + row;
    const float sg   = statb[((w * 16) + row) * 4 + 0];
    const int   ax   = __float_as_int(statb[((w * 16) + row) * 4 + 1]);
    const float m2av = statb[((w * 16) + row) * 4 + 2];
    const float m2bv = statb[((w * 16) + row) * 4 + 3];
    float ps0=0,ps1=0,ps2=0,ps3=0,ps4=0,ps5=0,ps6=0,ps7=0;
    float m1n0=0,m1n1=0,nq1a=0,nq1b=0;
    float m3n0=0,m3n1=0,nh0=0,nh1=0;
    float m4n0=0,m4n1=0,nq4a=0,nq4b=0;
#pragma unroll 5
    for (int k = 0; k < 25; ++k) {
      int h = k * 4 + hq;
      float pv = p[(size_t)h * BB * SS + (size_t)b * SS + gi];
      float hm = hmbuf[(size_t)(w * 16 + row) * 116 + h];
      float ql = qlast_s[h];
      float qi = q[(size_t)h * BB * SS + (size_t)b * SS + ax];
      float4 wv0 = *(const float4*)&wsq[h][0];
      float4 wv1 = *(const float4*)&wsq[h][4];
      float p2 = pv * pv;
      ps0 = fmaf(wv0.x, p2, ps0); ps1 = fmaf(wv0.y, p2, ps1);
      ps2 = fmaf(wv0.z, p2, ps2); ps3 = fmaf(wv0.w, p2, ps3);
      ps4 = fmaf(wv1.x, p2, ps4); ps5 = fmaf(wv1.y, p2, ps5);
      ps6 = fmaf(wv1.z, p2, ps6); ps7 = fmaf(wv1.w, p2, ps7);
      m1n0 = fmaf(wv0.x, pv * ql, m1n0); m1n1 = fmaf(wv0.y, pv * ql, m1n1);
      nq1a = fmaf(wv0.x, ql * ql, nq1a); nq1b = fmaf(wv0.y, ql * ql, nq1b);
      m3n0 = fmaf(wv1.x, pv * hm, m3n0); m3n1 = fmaf(wv1.y, pv * hm, m3n1);
      nh0  = fmaf(wv1.x, hm * hm, nh0);  nh1  = fmaf(wv1.y, hm * hm, nh1);
      m4n0 = fmaf(wv1.z, pv * qi, m4n0); m4n1 = fmaf(wv1.w, pv * qi, m4n1);
      nq4a = fmaf(wv1.z, qi * qi, nq4a); nq4b = fmaf(wv1.w, qi * qi, nq4b);
    }
#pragma unroll
    for (int m = 16; m < 64; m <<= 1) {
      ps0 += __shfl_xor(ps0, m);  ps1 += __shfl_xor(ps1, m);
      ps2 += __shfl_xor(ps2, m);  ps3 += __shfl_xor(ps3, m);
      ps4 += __shfl_xor(ps4, m);  ps5 += __shfl_xor(ps5, m);
      ps6 += __shfl_xor(ps6, m);  ps7 += __shfl_xor(ps7, m);
      m1n0 += __shfl_xor(m1n0, m); m1n1 += __shfl_xor(m1n1, m);
      nq1a += __shfl_xor(nq1a, m); nq1b += __shfl_xor(nq1b, m);
      m3n0 += __shfl_xor(m3n0, m); m3n1 += __shfl_xor(m3n1, m);
      nh0  += __shfl_xor(nh0,  m); nh1  += __shfl_xor(nh1,  m);
      m4n0 += __shfl_xor(m4n0, m); m4n1 += __shfl_xor(m4n1, m);
      nq4a += __shfl_xor(nq4a, m); nq4b += __shfl_xor(nq4b, m);
    }
    if (hq == 0) {
      const size_t base = (size_t)gi * (BB * 2) + (size_t)b * 2;
      out[(size_t)(0 + dir) * AS + base + 0] =
          m1n0 / (fmaxf(sqrtf(ps0), EPSF) * fmaxf(sqrtf(nq1a), EPSF));
      out[(size_t)(0 + dir) * AS + base + 1] =
          m1n1 / (fmaxf(sqrtf(ps1), EPSF) * fmaxf(sqrtf(nq1b), EPSF));
      out[(size_t)(2 + dir) * AS + base + 0] = m2av / fmaxf(sqrtf(ps2), EPSF);
      out[(size_t)(2 + dir) * AS + base + 1] = m2bv / fmaxf(sqrtf(ps3), EPSF);
      out[(size_t)(4 + dir) * AS + base + 0] =
          sg * m3n0 / (fmaxf(sqrtf(ps4), EPSF) * fmaxf(sqrtf(nh0), EPSF));
      out[(size_t)(4 + dir) * AS + base + 1] =
          sg * m3n1 / (fmaxf(sqrtf(ps5), EPSF) * fmaxf(sqrtf(nh1), EPSF));
      out[(size_t)(6 + dir) * AS + base + 0] =
          m4n0 / (fmaxf(sqrtf(ps6), EPSF) * fmaxf(sqrtf(nq4a), EPSF));
      out[(size_t)(6 + dir) * AS + base + 1] =
          m4n1 / (fmaxf(sqrtf(ps7), EPSF) * fmaxf(sqrtf(nq4b), EPSF));
    }
  }
}

extern "C" void kernel_launch(void* const* d_in, const int* in_sizes, int n_in,
                              void* d_out, int out_size, void* d_ws, size_t ws_size,
                              hipStream_t stream) {
  const float* pf  = (const float*)d_in[0];
  const float* pb  = (const float*)d_in[1];
  const float* qf  = (const float*)d_in[2];
  const float* qb  = (const float*)d_in[3];
  const float* w1f = (const float*)d_in[4];
  const float* w1b = (const float*)d_in[5];
  const float* w2f = (const float*)d_in[6];
  const float* w2b = (const float*)d_in[7];
  const float* w3f = (const float*)d_in[8];
  const float* w4f = (const float*)d_in[10];  // w3b/w4b unused by reference
  float* out = (float*)d_out;

  const size_t nq2_b  = (size_t)6 * BB * SS * 4;            //    589,824
  const size_t qhj_b  = (size_t)2 * HP * BB * SS * 2;       // 11,010,048
  float*    nq2    = (float*)d_ws;
  ushort_t* qhj_hi = (ushort_t*)((char*)d_ws + nq2_b);
  ushort_t* qTil   = (ushort_t*)((char*)d_ws + nq2_b + qhj_b);  // 26,738,688 B

  hipLaunchKernelGGL(qprep_kernel, dim3(2 * BB * 6), dim3(256), 0, stream,
                     qf, qb, w2f, w2b, nq2, qhj_hi, qTil);
  hipLaunchKernelGGL(bimpm_fused, dim3(2 * BB * 6), dim3(256), 0, stream,
                     pf, pb, qf, qb, w1f, w1b, w2f, w2b, w3f, w4f,
                     nq2, qhj_hi, qTil, out);
}